// Round 1
// baseline (461.959 us; speedup 1.0000x reference)
//
#include <hip/hip_runtime.h>

// CRF loss, B=512, S=1024, L=64 labels (+start/end -> C=66).
// One wave per batch element; lane = label state. Interior recursion closes
// over the 64 label states only (start/end contributions underflow to exactly
// 0.0f after max-subtraction: they sit at -1000 nats).
constexpr int B_ = 512;
constexpr int S_ = 1024;
constexpr int L_ = 64;
constexpr int C_ = 66;

__global__ void zero_out_k(float* o) { *o = 0.0f; }

__global__ __launch_bounds__(64) void crf_main_k(
    const float* __restrict__ pred,     // [B,S,L]
    const int*   __restrict__ ref,      // [B,S]
    const int*   __restrict__ seqlen,   // [B]
    const float* __restrict__ trans,    // [C,C]
    float*       __restrict__ out)      // [1]
{
    const int b    = blockIdx.x;
    const int lane = threadIdx.x;           // state j
    const int sl   = seqlen[b];             // 1..S
    const float* prow = pred + (size_t)b * (S_ * L_);

    // Register-resident exp(T): et[i] = exp(T[i][lane]), i = 0..63.
    float et[L_];
#pragma unroll
    for (int i = 0; i < L_; ++i)
        et[i] = __expf(trans[i * C_ + lane]);
    const float et_end = __expf(trans[lane * C_ + (L_ + 1)]);   // exp(T[j][65])

    // t = 1 (obs position 1): alpha_j = pred[0][j] + T[start][j]  (exact)
    float alpha = prow[lane] + trans[L_ * C_ + lane];

    // Software prefetch pipeline for pred rows (256B/row, coalesced dword/lane).
    constexpr int PF = 8;
    float pb[PF];
#pragma unroll
    for (int i = 0; i < PF; ++i) {
        const int r = 1 + i;
        pb[i] = (r < sl) ? prow[r * L_ + lane] : 0.0f;
    }

    // Interior steps t = 1 .. sl-1 consume pred row t.
    int t = 1;
    while (t < sl) {
#pragma unroll
        for (int u = 0; u < PF; ++u) {
            if (t >= sl) break;                       // wave-uniform branch
            const float pcur = pb[u];
            const int rn = t + PF;
            pb[u] = (rn < sl) ? prow[rn * L_ + lane] : 0.0f;   // prefetch

            // m = alpha[lane 0]; spread of alpha across states is bounded
            // (~+-15 nats), so exp stays comfortably inside fp32 range.
            const float m = __int_as_float(
                __builtin_amdgcn_readfirstlane(__float_as_int(alpha)));
            const float e = __expf(alpha - m);
            const int  ei = __float_as_int(e);

            // s_j = sum_i e_i * ET[i][j]; e_i broadcast via v_readlane.
            float a0 = 0.f, a1 = 0.f, a2 = 0.f, a3 = 0.f;
#pragma unroll
            for (int k = 0; k < L_; k += 4) {
                a0 = fmaf(__int_as_float(__builtin_amdgcn_readlane(ei, k    )), et[k    ], a0);
                a1 = fmaf(__int_as_float(__builtin_amdgcn_readlane(ei, k + 1)), et[k + 1], a1);
                a2 = fmaf(__int_as_float(__builtin_amdgcn_readlane(ei, k + 2)), et[k + 2], a2);
                a3 = fmaf(__int_as_float(__builtin_amdgcn_readlane(ei, k + 3)), et[k + 3], a3);
            }
            const float s = (a0 + a1) + (a2 + a3);
            alpha = pcur + (m + __logf(s));
            ++t;
        }
    }

    // Finalize: all_paths_b = max + log(sum_j exp(alpha_j - max) * exp(T[j][end]))
    float mx = alpha;
#pragma unroll
    for (int off = 32; off >= 1; off >>= 1)
        mx = fmaxf(mx, __shfl_xor(mx, off));
    float v = __expf(alpha - mx) * et_end;
#pragma unroll
    for (int off = 32; off >= 1; off >>= 1)
        v += __shfl_xor(v, off);
    const float all_paths = mx + __logf(v);

    // Gold path score (fused): emissions + transitions along the tagged path.
    const int* rrow = ref + (size_t)b * S_;
    float acc = 0.0f;
    for (int tt = lane; tt < sl; tt += 64) {
        const int r = rrow[tt];
        float x = prow[tt * L_ + r];                     // emission
        const int pr = (tt == 0) ? L_ : rrow[tt - 1];    // start or prev tag
        x += trans[pr * C_ + r];
        if (tt == sl - 1) x += trans[r * C_ + (L_ + 1)]; // -> end
        acc += x;
    }
#pragma unroll
    for (int off = 32; off >= 1; off >>= 1)
        acc += __shfl_xor(acc, off);

    if (lane == 0) atomicAdd(out, all_paths - acc);
}

extern "C" void kernel_launch(void* const* d_in, const int* in_sizes, int n_in,
                              void* d_out, int out_size, void* d_ws, size_t ws_size,
                              hipStream_t stream) {
    const float* pred   = (const float*)d_in[0];
    const int*   ref    = (const int*)d_in[1];
    const int*   seqlen = (const int*)d_in[2];
    const float* trans  = (const float*)d_in[3];
    float* out = (float*)d_out;

    zero_out_k<<<1, 1, 0, stream>>>(out);
    crf_main_k<<<B_, 64, 0, stream>>>(pred, ref, seqlen, trans, out);
}